// Round 19
// baseline (182.080 us; speedup 1.0000x reference)
//
#include <hip/hip_runtime.h>

#define HW 1659      // 21*79
#define PADID 4096
#define EMB 20
#define HID 32
#define MAXLEN 64

typedef float v2f __attribute__((ext_vector_type(2)));

// DPP lane-permute helper (pure VALU, no LDS pipe). CTRL is an immediate.
template <int CTRL>
__device__ __forceinline__ float dppf(float v) {
    return __builtin_bit_cast(float,
        __builtin_amdgcn_update_dpp(0, __builtin_bit_cast(int, v),
                                    CTRL, 0xF, 0xF, true));
}
#define DPP_XOR1 0xB1   // quad_perm [1,0,3,2]
#define DPP_XOR2 0x4E   // quad_perm [2,3,0,1]
#define DPP_XOR7 0x141  // row_half_mirror (xor 7 within 16)
#define DPP_XORF 0x140  // row_mirror      (xor 15 within 16)

// ---------------- Kernel 0: proj[g][j] = emb_table[g] . W_ih[j]  ---------------
__global__ __launch_bounds__(128) void proj_kernel(
    const float* __restrict__ emb_table, const float* __restrict__ W_ih,
    float* __restrict__ proj)
{
    const int tid = threadIdx.x;
    const int g = blockIdx.x * 4 + (tid >> 5);
    const int j = tid & 31;
    if (g > PADID) return;               // 4097 rows (row 4096 = zeros)
    const float* er = emb_table + (size_t)g * EMB;
    const float* wr = W_ih + j * EMB;
    float s = 0.f;
#pragma unroll
    for (int k = 0; k < EMB; k++) s += wr[k] * er[k];
    proj[(size_t)g * HID + j] = s;
}

// ---------------- Kernel 1: 128-thread blocks -> 16 independent blocks/CU ------
// Same algorithm as the proven R12 kernel, re-partitioned: 2 waves/block means
// 16 resident blocks/CU (vs 8) = 2x independent load->scatter->scan latency
// chains overlapping per CU. Per-thread work doubles (VALU was 78% idle).
__global__ __launch_bounds__(128) void bag_emb_kernel(
    const int* __restrict__ chars, const int* __restrict__ colors,
    const float* __restrict__ emb_table,
    float* __restrict__ out_emb, float* __restrict__ out_bag)
{
    __shared__ unsigned char pres[4096];
    __shared__ int bagl[64];
    __shared__ int wsum[2];

    const int b   = blockIdx.x;
    const int tid = threadIdx.x;
    const int lane = tid & 63;
    const int wv   = tid >> 6;           // wave 0/1

    // ---- hoisted global loads: 4 int4-pairs per thread + peel/tail ----
    const int base = b * HW;
    const int pe = (4 - (base & 3)) & 3;          // peel to 16B alignment
    const int nv = (HW - pe) >> 2;                // 413/414 int4 groups
    const int nt = HW - pe - (nv << 2);           // tail 0..3
    const int4* c4 = (const int4*)(chars + base + pe);
    const int4* k4 = (const int4*)(colors + base + pe);

    // tid, tid+128, tid+256 always < nv (383 < 413); tid+384 conditional
    int4 ca = c4[tid],       ka = k4[tid];
    int4 cb = c4[tid + 128], kb = k4[tid + 128];
    int4 cc = c4[tid + 256], kc = k4[tid + 256];
    const bool has4 = (tid + 384) < nv;
    const int i4 = has4 ? tid + 384 : tid;
    int4 cd = c4[i4], kd = k4[i4];
    int gp = -1, gt = -1;
    if (tid < pe) gp = (chars[base + tid] << 4) + colors[base + tid];
    if (tid < nt) {
        int i = base + pe + (nv << 2) + tid;
        gt = (chars[i] << 4) + colors[i];
    }

    // zero pres (256 uint4 by 128 threads: 2 each) + bagl init
    uint4* pz = (uint4*)pres;
    pz[tid]       = make_uint4(0u, 0u, 0u, 0u);
    pz[tid + 128] = make_uint4(0u, 0u, 0u, 0u);
    if (tid < 64) bagl[tid] = PADID;
    __syncthreads();

    // ---- scatter presence bytes (idempotent, no atomics) ----
    pres[(ca.x << 4) + ka.x] = 1;
    pres[(ca.y << 4) + ka.y] = 1;
    pres[(ca.z << 4) + ka.z] = 1;
    pres[(ca.w << 4) + ka.w] = 1;
    pres[(cb.x << 4) + kb.x] = 1;
    pres[(cb.y << 4) + kb.y] = 1;
    pres[(cb.z << 4) + kb.z] = 1;
    pres[(cb.w << 4) + kb.w] = 1;
    pres[(cc.x << 4) + kc.x] = 1;
    pres[(cc.y << 4) + kc.y] = 1;
    pres[(cc.z << 4) + kc.z] = 1;
    pres[(cc.w << 4) + kc.w] = 1;
    if (has4) {
        pres[(cd.x << 4) + kd.x] = 1;
        pres[(cd.y << 4) + kd.y] = 1;
        pres[(cd.z << 4) + kd.z] = 1;
        pres[(cd.w << 4) + kd.w] = 1;
    }
    if (gp >= 0) pres[gp] = 1;
    if (gt >= 0) pres[gt] = 1;
    __syncthreads();

    // ---- thread owns 32 contiguous ids [32*tid, 32*tid+32) ----
    uint4 q0 = pz[2 * tid], q1 = pz[2 * tid + 1];
    const unsigned M = 0x01010101u;
    int cnt = __popc(q0.x & M) + __popc(q0.y & M) + __popc(q0.z & M) + __popc(q0.w & M)
            + __popc(q1.x & M) + __popc(q1.y & M) + __popc(q1.z & M) + __popc(q1.w & M);

    int pre = cnt;                        // wave inclusive scan
#pragma unroll
    for (int d = 1; d < 64; d <<= 1) {
        int v = __shfl_up(pre, d, 64);
        if (lane >= d) pre += v;
    }
    if (lane == 63) wsum[wv] = pre;
    __syncthreads();
    const int wbase = (wv == 1) ? wsum[0] : 0;
    int p = wbase + pre - cnt;            // exclusive prefix

    if (p < 64) {                         // only low-prefix threads extract
        unsigned wrd[8] = {q0.x, q0.y, q0.z, q0.w, q1.x, q1.y, q1.z, q1.w};
#pragma unroll
        for (int c = 0; c < 8; c++) {
#pragma unroll
            for (int k = 0; k < 4; k++) {
                if ((wrd[c] >> (8 * k)) & 1) {
                    if (p < 64) bagl[p] = 32 * tid + 4 * c + k;
                    p++;
                }
            }
        }
    }
    __syncthreads();

    if (tid < 64) out_bag[(size_t)b * 64 + tid] = (float)bagl[tid];

    // ---- gather: 320 float4 by 128 threads ----
    const float4* tab4 = (const float4*)emb_table;
    float4* dst4 = (float4*)(out_emb + (size_t)b * (MAXLEN * EMB));
    for (int q = tid; q < MAXLEN * 5; q += 128) {
        int t = q / 5;
        int m = q - t * 5;
        int row = bagl[t];
        dst4[q] = tab4[row * 5 + m];
    }
}

// ------- Kernel 2: packed RNN, DPP all-gather, FULL pv preload (R18 exact) -----
__global__ __launch_bounds__(128)
__attribute__((amdgpu_waves_per_eu(2, 2)))
void rnn_kernel(
    const float* __restrict__ proj, const float* __restrict__ bagf,
    const float* __restrict__ W_hh,
    const float* __restrict__ b_ih, const float* __restrict__ b_hh,
    float* __restrict__ out_h)
{
    const int tid  = threadIdx.x;
    const int wv   = tid >> 6;
    const int lane = tid & 63;
    const int sl   = lane >> 4;        // sample slot within wave 0..3
    const int ib   = wv * 4 + sl;      // sample slot within block 0..7
    const int jj   = lane & 15;        // owns hidden units 2jj, 2jj+1
    const int b    = blockIdx.x * 8 + ib;

    const int GMAP[16] = {0,1,2,3, 7,6,5,4, 15,14,13,12,11,10,9,8};

    v2f w0[16], w1[16];
    const float2* wr0 = (const float2*)(W_hh + (2 * jj) * HID);
    const float2* wr1 = (const float2*)(W_hh + (2 * jj + 1) * HID);
#pragma unroll
    for (int m = 0; m < 16; m++) {
        const int c = jj ^ GMAP[m];
        float2 a = wr0[c], bb = wr1[c];
        w0[m] = (v2f){a.x, a.y};
        w1[m] = (v2f){bb.x, bb.y};
    }
    const float sb0 = b_ih[2 * jj]     + b_hh[2 * jj];
    const float sb1 = b_ih[2 * jj + 1] + b_hh[2 * jj + 1];

    const float* bps = bagf + (size_t)b * 64;
    const float2* proj2 = (const float2*)proj;   // row g -> proj2[g*16 + jj]

    // ---- preload chunk A: t = 0..31 ----
    float2 pvA[32];
    int lenA = 0;
    {
        int idx[32];
#pragma unroll
        for (int t = 0; t < 32; t++) idx[t] = (int)bps[t];
#pragma unroll
        for (int t = 0; t < 32; t++) {
            lenA += (idx[t] < PADID) ? 1 : 0;
            pvA[t] = proj2[idx[t] * 16 + jj];    // row 4096 is all zeros
        }
    }

    float h0 = 0.f, h1 = 0.f;

#pragma unroll
    for (int t = 0; t < 32; t++) {
        v2f g[16];
        g[0] = (v2f){h0, h1};
        g[1] = (v2f){dppf<DPP_XOR1>(g[0].x), dppf<DPP_XOR1>(g[0].y)};
        g[2] = (v2f){dppf<DPP_XOR2>(g[0].x), dppf<DPP_XOR2>(g[0].y)};
        g[3] = (v2f){dppf<DPP_XOR2>(g[1].x), dppf<DPP_XOR2>(g[1].y)};
#pragma unroll
        for (int m = 0; m < 4; m++)
            g[4 + m] = (v2f){dppf<DPP_XOR7>(g[m].x), dppf<DPP_XOR7>(g[m].y)};
#pragma unroll
        for (int m = 0; m < 8; m++)
            g[8 + m] = (v2f){dppf<DPP_XORF>(g[m].x), dppf<DPP_XORF>(g[m].y)};

        v2f a0 = (v2f){0.f, 0.f}, b0 = a0, a1 = a0, b1 = a0;
#pragma unroll
        for (int m = 0; m < 16; m += 2) {
            a0 = __builtin_elementwise_fma(w0[m],     g[m],     a0);
            b0 = __builtin_elementwise_fma(w0[m + 1], g[m + 1], b0);
            a1 = __builtin_elementwise_fma(w1[m],     g[m],     a1);
            b1 = __builtin_elementwise_fma(w1[m + 1], g[m + 1], b1);
        }
        float s0 = sb0 + pvA[t].x + (a0.x + a0.y) + (b0.x + b0.y);
        float s1 = sb1 + pvA[t].y + (a1.x + a1.y) + (b1.x + b1.y);

        float e0 = __expf(2.f * s0);
        float e1 = __expf(2.f * s1);
        float th0 = 1.f - 2.f * __builtin_amdgcn_rcpf(e0 + 1.f);
        float th1 = 1.f - 2.f * __builtin_amdgcn_rcpf(e1 + 1.f);

        h0 = (t < lenA) ? th0 : h0;
        h1 = (t < lenA) ? th1 : h1;
    }

    // ---- preload chunk B: t = 32..63 ----
    float2 pvB[32];
    int lenB = 0;
    {
        int idx[32];
#pragma unroll
        for (int t = 0; t < 32; t++) idx[t] = (int)bps[32 + t];
#pragma unroll
        for (int t = 0; t < 32; t++) {
            lenB += (idx[t] < PADID) ? 1 : 0;
            pvB[t] = proj2[idx[t] * 16 + jj];
        }
    }
    const int len = lenA + lenB;       // exact: bag sorted (lenA<32 => lenB==0)

#pragma unroll
    for (int t2 = 0; t2 < 32; t2++) {
        const int t = 32 + t2;
        v2f g[16];
        g[0] = (v2f){h0, h1};
        g[1] = (v2f){dppf<DPP_XOR1>(g[0].x), dppf<DPP_XOR1>(g[0].y)};
        g[2] = (v2f){dppf<DPP_XOR2>(g[0].x), dppf<DPP_XOR2>(g[0].y)};
        g[3] = (v2f){dppf<DPP_XOR2>(g[1].x), dppf<DPP_XOR2>(g[1].y)};
#pragma unroll
        for (int m = 0; m < 4; m++)
            g[4 + m] = (v2f){dppf<DPP_XOR7>(g[m].x), dppf<DPP_XOR7>(g[m].y)};
#pragma unroll
        for (int m = 0; m < 8; m++)
            g[8 + m] = (v2f){dppf<DPP_XORF>(g[m].x), dppf<DPP_XORF>(g[m].y)};

        v2f a0 = (v2f){0.f, 0.f}, b0 = a0, a1 = a0, b1 = a0;
#pragma unroll
        for (int m = 0; m < 16; m += 2) {
            a0 = __builtin_elementwise_fma(w0[m],     g[m],     a0);
            b0 = __builtin_elementwise_fma(w0[m + 1], g[m + 1], b0);
            a1 = __builtin_elementwise_fma(w1[m],     g[m],     a1);
            b1 = __builtin_elementwise_fma(w1[m + 1], g[m + 1], b1);
        }
        float s0 = sb0 + pvB[t2].x + (a0.x + a0.y) + (b0.x + b0.y);
        float s1 = sb1 + pvB[t2].y + (a1.x + a1.y) + (b1.x + b1.y);

        float e0 = __expf(2.f * s0);
        float e1 = __expf(2.f * s1);
        float th0 = 1.f - 2.f * __builtin_amdgcn_rcpf(e0 + 1.f);
        float th1 = 1.f - 2.f * __builtin_amdgcn_rcpf(e1 + 1.f);

        h0 = (t < len) ? th0 : h0;
        h1 = (t < len) ? th1 : h1;
    }

    ((float2*)(out_h + (size_t)b * HID))[jj] = make_float2(h0, h1);
}

// ---------------- Fallback RNN (R4 exact) if ws can't hold proj ----------------
__global__ __launch_bounds__(128, 4) void rnn_kernel_noproj(
    const float* __restrict__ emb, const float* __restrict__ bagf,
    const float* __restrict__ W_ih, const float* __restrict__ W_hh,
    const float* __restrict__ b_ih, const float* __restrict__ b_hh,
    float* __restrict__ out_h)
{
    __shared__ float hbuf[4][32];
    const int tid = threadIdx.x;
    const int ib  = tid >> 5;
    const int j   = tid & 31;
    const int b   = blockIdx.x * 4 + ib;

    float wih[EMB];
#pragma unroll
    for (int k = 0; k < EMB; k++) wih[k] = W_ih[j * EMB + k];
    float whh[HID];
#pragma unroll
    for (int k = 0; k < HID; k++) whh[k] = W_hh[j * HID + k];
    const float sbias = b_ih[j] + b_hh[j];

    const float* bp = bagf + (size_t)b * 64;
    unsigned long long m0 = __ballot(bp[j]      < 4095.5f);
    unsigned long long m1 = __ballot(bp[32 + j] < 4095.5f);
    const int half = ib & 1;
    const int len = __popc((unsigned)(m0 >> (half * 32)))
                  + __popc((unsigned)(m1 >> (half * 32)));

    hbuf[ib][j] = 0.f;
    asm volatile("s_waitcnt lgkmcnt(0)" ::: "memory");

    float h = 0.f;
    const float* xb = emb + (size_t)b * (MAXLEN * EMB);
    for (int t = 0; t < MAXLEN; t++) {
        const float4* xp = (const float4*)(xb + t * EMB);
        float4 x0 = xp[0], x1 = xp[1], x2 = xp[2], x3 = xp[3], x4 = xp[4];
        float s = sbias;
        const float4* hb4 = (const float4*)hbuf[ib];
#pragma unroll
        for (int m = 0; m < 8; m++) {
            float4 hv = hb4[m];
            s += whh[4*m+0]*hv.x + whh[4*m+1]*hv.y
               + whh[4*m+2]*hv.z + whh[4*m+3]*hv.w;
        }
        s += wih[0]*x0.x + wih[1]*x0.y + wih[2]*x0.z + wih[3]*x0.w;
        s += wih[4]*x1.x + wih[5]*x1.y + wih[6]*x1.z + wih[7]*x1.w;
        s += wih[8]*x2.x + wih[9]*x2.y + wih[10]*x2.z + wih[11]*x2.w;
        s += wih[12]*x3.x + wih[13]*x3.y + wih[14]*x3.z + wih[15]*x3.w;
        s += wih[16]*x4.x + wih[17]*x4.y + wih[18]*x4.z + wih[19]*x4.w;
        s = fminf(fmaxf(s, -9.f), 9.f);
        float e = __expf(2.f * s);
        float th = (e - 1.f) * __builtin_amdgcn_rcpf(e + 1.f);
        h = (t < len) ? th : h;
        hbuf[ib][j] = h;
        asm volatile("s_waitcnt lgkmcnt(0)" ::: "memory");
    }
    out_h[(size_t)b * HID + j] = h;
}

extern "C" void kernel_launch(void* const* d_in, const int* in_sizes, int n_in,
                              void* d_out, int out_size, void* d_ws, size_t ws_size,
                              hipStream_t stream) {
    const int*   chars     = (const int*)d_in[0];
    const int*   colors    = (const int*)d_in[1];
    const float* emb_table = (const float*)d_in[2];
    const float* W_ih      = (const float*)d_in[3];
    const float* W_hh      = (const float*)d_in[4];
    const float* b_ih      = (const float*)d_in[5];
    const float* b_hh      = (const float*)d_in[6];

    const int B = in_sizes[0] / HW;      // 8192

    float* out     = (float*)d_out;
    float* out_h   = out;                                    // [B, 32]
    float* out_emb = out + (size_t)B * HID;                  // [B, 64, 20]
    float* out_bag = out_emb + (size_t)B * MAXLEN * EMB;     // [B, 64]

    const size_t proj_bytes = (size_t)(PADID + 1) * HID * sizeof(float);

    bag_emb_kernel<<<B, 128, 0, stream>>>(chars, colors, emb_table, out_emb, out_bag);

    if (ws_size >= proj_bytes) {         // ws_size is fixed -> same path every call
        float* proj = (float*)d_ws;
        proj_kernel<<<(PADID + 1 + 3) / 4, 128, 0, stream>>>(emb_table, W_ih, proj);
        rnn_kernel<<<B / 8, 128, 0, stream>>>(proj, out_bag, W_hh, b_ih, b_hh, out_h);
    } else {
        rnn_kernel_noproj<<<B / 4, 128, 0, stream>>>(out_emb, out_bag, W_ih, W_hh,
                                                     b_ih, b_hh, out_h);
    }
}

// Round 20
// 180.488 us; speedup vs baseline: 1.0088x; 1.0088x over previous
//
#include <hip/hip_runtime.h>

#define HW 1659      // 21*79
#define PADID 4096
#define EMB 20
#define HID 32
#define MAXLEN 64

typedef float v2f __attribute__((ext_vector_type(2)));

// DPP lane-permute helper (pure VALU, no LDS pipe). CTRL is an immediate.
template <int CTRL>
__device__ __forceinline__ float dppf(float v) {
    return __builtin_bit_cast(float,
        __builtin_amdgcn_update_dpp(0, __builtin_bit_cast(int, v),
                                    CTRL, 0xF, 0xF, true));
}
#define DPP_XOR1 0xB1   // quad_perm [1,0,3,2]
#define DPP_XOR2 0x4E   // quad_perm [2,3,0,1]
#define DPP_XOR7 0x141  // row_half_mirror (xor 7 within 16)
#define DPP_XORF 0x140  // row_mirror      (xor 15 within 16)

// ---------------- Kernel 0: proj[g][j] = emb_table[g] . W_ih[j]  ---------------
__global__ __launch_bounds__(128) void proj_kernel(
    const float* __restrict__ emb_table, const float* __restrict__ W_ih,
    float* __restrict__ proj)
{
    const int tid = threadIdx.x;
    const int g = blockIdx.x * 4 + (tid >> 5);
    const int j = tid & 31;
    if (g > PADID) return;               // 4097 rows (row 4096 = zeros)
    const float* er = emb_table + (size_t)g * EMB;
    const float* wr = W_ih + j * EMB;
    float s = 0.f;
#pragma unroll
    for (int k = 0; k < EMB; k++) s += wr[k] * er[k];
    proj[(size_t)g * HID + j] = s;
}

// ---------------- Kernel 1: block-per-sample, HOISTED loads (R18/R12 exact) ----
__global__ __launch_bounds__(256) void bag_emb_kernel(
    const int* __restrict__ chars, const int* __restrict__ colors,
    const float* __restrict__ emb_table,
    float* __restrict__ out_emb, float* __restrict__ out_bag)
{
    __shared__ unsigned char pres[4096];
    __shared__ int bagl[64];
    __shared__ int wsum[4];

    const int b   = blockIdx.x;
    const int tid = threadIdx.x;
    const int lane = tid & 63;
    const int wv   = tid >> 6;

    const int base = b * HW;
    const int pe = (4 - (base & 3)) & 3;          // peel to 16B alignment
    const int nv = (HW - pe) >> 2;                // 413/414 int4 groups
    const int nt = HW - pe - (nv << 2);           // tail 0..3
    const int4* c4 = (const int4*)(chars + base + pe);
    const int4* k4 = (const int4*)(colors + base + pe);

    int4 ca = c4[tid], ka = k4[tid];              // tid < nv always (nv>=413)
    const bool has2 = (tid + 256) < nv;
    const int i2 = has2 ? tid + 256 : tid;
    int4 cb = c4[i2], kb = k4[i2];
    int gp = -1, gt = -1;
    if (tid < pe) gp = (chars[base + tid] << 4) + colors[base + tid];
    if (tid < nt) {
        int i = base + pe + (nv << 2) + tid;
        gt = (chars[i] << 4) + colors[i];
    }

    ((uint4*)pres)[tid] = make_uint4(0u, 0u, 0u, 0u);
    if (tid < 64) bagl[tid] = PADID;
    __syncthreads();

    pres[(ca.x << 4) + ka.x] = 1;
    pres[(ca.y << 4) + ka.y] = 1;
    pres[(ca.z << 4) + ka.z] = 1;
    pres[(ca.w << 4) + ka.w] = 1;
    if (has2) {
        pres[(cb.x << 4) + kb.x] = 1;
        pres[(cb.y << 4) + kb.y] = 1;
        pres[(cb.z << 4) + kb.z] = 1;
        pres[(cb.w << 4) + kb.w] = 1;
    }
    if (gp >= 0) pres[gp] = 1;
    if (gt >= 0) pres[gt] = 1;
    __syncthreads();

    uint4 w4 = ((const uint4*)pres)[tid];
    const unsigned M = 0x01010101u;
    int cnt = __popc(w4.x & M) + __popc(w4.y & M)
            + __popc(w4.z & M) + __popc(w4.w & M);

    int pre = cnt;
#pragma unroll
    for (int d = 1; d < 64; d <<= 1) {
        int v = __shfl_up(pre, d, 64);
        if (lane >= d) pre += v;
    }
    if (lane == 63) wsum[wv] = pre;
    __syncthreads();
    int wbase = 0;
#pragma unroll
    for (int w2 = 0; w2 < 4; w2++) wbase += (w2 < wv) ? wsum[w2] : 0;
    int p = wbase + pre - cnt;

    unsigned wrd[4] = {w4.x, w4.y, w4.z, w4.w};
#pragma unroll
    for (int c = 0; c < 4; c++) {
#pragma unroll
        for (int k = 0; k < 4; k++) {
            if ((wrd[c] >> (8 * k)) & 1) {
                if (p < 64) bagl[p] = 16 * tid + 4 * c + k;
                p++;
            }
        }
    }
    __syncthreads();

    if (tid < 64) out_bag[(size_t)b * 64 + tid] = (float)bagl[tid];

    const float4* tab4 = (const float4*)emb_table;
    float4* dst4 = (float4*)(out_emb + (size_t)b * (MAXLEN * EMB));
    for (int q = tid; q < MAXLEN * 5; q += 256) {
        int t = q / 5;
        int m = q - t * 5;
        int row = bagl[t];
        dst4[q] = tab4[row * 5 + m];
    }
}

// ------ Kernel 2: packed RNN, DPP all-gather, CHUNKED pv preload (16-deep) -----
// R18's full 32-deep preload spilled (VGPR=88 < needed ~180). 16-deep chunks
// need ~130 VGPRs total -> fits without spill. Freeze condition simplified:
// bag is sorted, so (t < len) == (bag[t] < PADID) -> no ballots, no len.
__global__ __launch_bounds__(128)
__attribute__((amdgpu_waves_per_eu(2, 2)))
void rnn_kernel(
    const float* __restrict__ proj, const float* __restrict__ bagf,
    const float* __restrict__ W_hh,
    const float* __restrict__ b_ih, const float* __restrict__ b_hh,
    float* __restrict__ out_h)
{
    const int tid  = threadIdx.x;
    const int wv   = tid >> 6;
    const int lane = tid & 63;
    const int sl   = lane >> 4;        // sample slot within wave 0..3
    const int ib   = wv * 4 + sl;      // sample slot within block 0..7
    const int jj   = lane & 15;        // owns hidden units 2jj, 2jj+1
    const int b    = blockIdx.x * 8 + ib;

    // gather-position -> pair-xor map (butterfly: xor1, xor2, xor7, xor15)
    const int GMAP[16] = {0,1,2,3, 7,6,5,4, 15,14,13,12,11,10,9,8};

    // weights: w0[m]/w1[m] = rows (2jj, 2jj+1), column pair c = jj ^ GMAP[m]
    v2f w0[16], w1[16];
    const float2* wr0 = (const float2*)(W_hh + (2 * jj) * HID);
    const float2* wr1 = (const float2*)(W_hh + (2 * jj + 1) * HID);
#pragma unroll
    for (int m = 0; m < 16; m++) {
        const int c = jj ^ GMAP[m];
        float2 a = wr0[c], bb = wr1[c];
        w0[m] = (v2f){a.x, a.y};
        w1[m] = (v2f){bb.x, bb.y};
    }
    const float sb0 = b_ih[2 * jj]     + b_hh[2 * jj];
    const float sb1 = b_ih[2 * jj + 1] + b_hh[2 * jj + 1];

    const float* bps = bagf + (size_t)b * 64;
    const float2* proj2 = (const float2*)proj;   // row g -> proj2[g*16 + jj]

    float h0 = 0.f, h1 = 0.f;

#pragma unroll
    for (int ch = 0; ch < 4; ch++) {
        // ---- preload this chunk's 16 idx + pv (independent loads, MLP) ----
        int idx[16];
#pragma unroll
        for (int i = 0; i < 16; i++) idx[i] = (int)bps[ch * 16 + i];
        float2 pv[16];
#pragma unroll
        for (int i = 0; i < 16; i++) pv[i] = proj2[idx[i] * 16 + jj];

#pragma unroll
        for (int i = 0; i < 16; i++) {
            // sorted bag: (t < len) <=> bag[t] != PAD
            const bool upd = idx[i] < PADID;

            // ---- DPP butterfly all-gather: g[m] = pair (jj ^ GMAP[m]) ----
            v2f g[16];
            g[0] = (v2f){h0, h1};
            g[1] = (v2f){dppf<DPP_XOR1>(g[0].x), dppf<DPP_XOR1>(g[0].y)};
            g[2] = (v2f){dppf<DPP_XOR2>(g[0].x), dppf<DPP_XOR2>(g[0].y)};
            g[3] = (v2f){dppf<DPP_XOR2>(g[1].x), dppf<DPP_XOR2>(g[1].y)};
#pragma unroll
            for (int m = 0; m < 4; m++)
                g[4 + m] = (v2f){dppf<DPP_XOR7>(g[m].x), dppf<DPP_XOR7>(g[m].y)};
#pragma unroll
            for (int m = 0; m < 8; m++)
                g[8 + m] = (v2f){dppf<DPP_XORF>(g[m].x), dppf<DPP_XORF>(g[m].y)};

            // ---- 32 pk_fma: rows 2jj and 2jj+1 ----
            v2f a0 = (v2f){0.f, 0.f}, b0 = a0, a1 = a0, b1 = a0;
#pragma unroll
            for (int m = 0; m < 16; m += 2) {
                a0 = __builtin_elementwise_fma(w0[m],     g[m],     a0);
                b0 = __builtin_elementwise_fma(w0[m + 1], g[m + 1], b0);
                a1 = __builtin_elementwise_fma(w1[m],     g[m],     a1);
                b1 = __builtin_elementwise_fma(w1[m + 1], g[m + 1], b1);
            }
            float s0 = sb0 + pv[i].x + (a0.x + a0.y) + (b0.x + b0.y);
            float s1 = sb1 + pv[i].y + (a1.x + a1.y) + (b1.x + b1.y);

            // tanh(s) = 1 - 2/(e^{2s}+1); robust at both extremes, no clamp
            float e0 = __expf(2.f * s0);
            float e1 = __expf(2.f * s1);
            float th0 = 1.f - 2.f * __builtin_amdgcn_rcpf(e0 + 1.f);
            float th1 = 1.f - 2.f * __builtin_amdgcn_rcpf(e1 + 1.f);

            h0 = upd ? th0 : h0;
            h1 = upd ? th1 : h1;
        }
    }

    ((float2*)(out_h + (size_t)b * HID))[jj] = make_float2(h0, h1);
}

// ---------------- Fallback RNN (R4 exact) if ws can't hold proj ----------------
__global__ __launch_bounds__(128, 4) void rnn_kernel_noproj(
    const float* __restrict__ emb, const float* __restrict__ bagf,
    const float* __restrict__ W_ih, const float* __restrict__ W_hh,
    const float* __restrict__ b_ih, const float* __restrict__ b_hh,
    float* __restrict__ out_h)
{
    __shared__ float hbuf[4][32];
    const int tid = threadIdx.x;
    const int ib  = tid >> 5;
    const int j   = tid & 31;
    const int b   = blockIdx.x * 4 + ib;

    float wih[EMB];
#pragma unroll
    for (int k = 0; k < EMB; k++) wih[k] = W_ih[j * EMB + k];
    float whh[HID];
#pragma unroll
    for (int k = 0; k < HID; k++) whh[k] = W_hh[j * HID + k];
    const float sbias = b_ih[j] + b_hh[j];

    const float* bp = bagf + (size_t)b * 64;
    unsigned long long m0 = __ballot(bp[j]      < 4095.5f);
    unsigned long long m1 = __ballot(bp[32 + j] < 4095.5f);
    const int half = ib & 1;
    const int len = __popc((unsigned)(m0 >> (half * 32)))
                  + __popc((unsigned)(m1 >> (half * 32)));

    hbuf[ib][j] = 0.f;
    asm volatile("s_waitcnt lgkmcnt(0)" ::: "memory");

    float h = 0.f;
    const float* xb = emb + (size_t)b * (MAXLEN * EMB);
    for (int t = 0; t < MAXLEN; t++) {
        const float4* xp = (const float4*)(xb + t * EMB);
        float4 x0 = xp[0], x1 = xp[1], x2 = xp[2], x3 = xp[3], x4 = xp[4];
        float s = sbias;
        const float4* hb4 = (const float4*)hbuf[ib];
#pragma unroll
        for (int m = 0; m < 8; m++) {
            float4 hv = hb4[m];
            s += whh[4*m+0]*hv.x + whh[4*m+1]*hv.y
               + whh[4*m+2]*hv.z + whh[4*m+3]*hv.w;
        }
        s += wih[0]*x0.x + wih[1]*x0.y + wih[2]*x0.z + wih[3]*x0.w;
        s += wih[4]*x1.x + wih[5]*x1.y + wih[6]*x1.z + wih[7]*x1.w;
        s += wih[8]*x2.x + wih[9]*x2.y + wih[10]*x2.z + wih[11]*x2.w;
        s += wih[12]*x3.x + wih[13]*x3.y + wih[14]*x3.z + wih[15]*x3.w;
        s += wih[16]*x4.x + wih[17]*x4.y + wih[18]*x4.z + wih[19]*x4.w;
        s = fminf(fmaxf(s, -9.f), 9.f);
        float e = __expf(2.f * s);
        float th = (e - 1.f) * __builtin_amdgcn_rcpf(e + 1.f);
        h = (t < len) ? th : h;
        hbuf[ib][j] = h;
        asm volatile("s_waitcnt lgkmcnt(0)" ::: "memory");
    }
    out_h[(size_t)b * HID + j] = h;
}

extern "C" void kernel_launch(void* const* d_in, const int* in_sizes, int n_in,
                              void* d_out, int out_size, void* d_ws, size_t ws_size,
                              hipStream_t stream) {
    const int*   chars     = (const int*)d_in[0];
    const int*   colors    = (const int*)d_in[1];
    const float* emb_table = (const float*)d_in[2];
    const float* W_ih      = (const float*)d_in[3];
    const float* W_hh      = (const float*)d_in[4];
    const float* b_ih      = (const float*)d_in[5];
    const float* b_hh      = (const float*)d_in[6];

    const int B = in_sizes[0] / HW;      // 8192

    float* out     = (float*)d_out;
    float* out_h   = out;                                    // [B, 32]
    float* out_emb = out + (size_t)B * HID;                  // [B, 64, 20]
    float* out_bag = out_emb + (size_t)B * MAXLEN * EMB;     // [B, 64]

    const size_t proj_bytes = (size_t)(PADID + 1) * HID * sizeof(float);

    bag_emb_kernel<<<B, 256, 0, stream>>>(chars, colors, emb_table, out_emb, out_bag);

    if (ws_size >= proj_bytes) {         // ws_size is fixed -> same path every call
        float* proj = (float*)d_ws;
        proj_kernel<<<(PADID + 1 + 3) / 4, 128, 0, stream>>>(emb_table, W_ih, proj);
        rnn_kernel<<<B / 8, 128, 0, stream>>>(proj, out_bag, W_hh, b_ih, b_hh, out_h);
    } else {
        rnn_kernel_noproj<<<B / 4, 128, 0, stream>>>(out_emb, out_bag, W_ih, W_hh,
                                                     b_ih, b_hh, out_h);
    }
}